// Round 5
// baseline (534.687 us; speedup 1.0000x reference)
//
#include <hip/hip_runtime.h>
#include <math.h>

typedef unsigned short ushort_t;
typedef short bf16x8 __attribute__((ext_vector_type(8)));
typedef unsigned short u16x8 __attribute__((ext_vector_type(8)));
typedef float f32x4 __attribute__((ext_vector_type(4)));

__device__ __forceinline__ float wsum64(float v) {
#pragma unroll
  for (int off = 32; off > 0; off >>= 1) v += __shfl_xor(v, off, 64);
  return v;
}

__device__ __forceinline__ ushort_t f2bf(float x) {   // RNE f32->bf16
  unsigned u = __float_as_uint(x);
  return (ushort_t)((u + 0x7fffu + ((u >> 16) & 1u)) >> 16);
}
__device__ __forceinline__ float bf2f(ushort_t h) {
  return __uint_as_float(((unsigned)h) << 16);
}

__device__ __forceinline__ void split8(const float4 a, const float4 b,
                                       u16x8& h, u16x8& l) {
  h[0]=f2bf(a.x); l[0]=f2bf(a.x-bf2f(h[0]));
  h[1]=f2bf(a.y); l[1]=f2bf(a.y-bf2f(h[1]));
  h[2]=f2bf(a.z); l[2]=f2bf(a.z-bf2f(h[2]));
  h[3]=f2bf(a.w); l[3]=f2bf(a.w-bf2f(h[3]));
  h[4]=f2bf(b.x); l[4]=f2bf(b.x-bf2f(h[4]));
  h[5]=f2bf(b.y); l[5]=f2bf(b.y-bf2f(h[5]));
  h[6]=f2bf(b.z); l[6]=f2bf(b.z-bf2f(h[6]));
  h[7]=f2bf(b.w); l[7]=f2bf(b.w-bf2f(h[7]));
}

// async global(per-lane) -> LDS(wave-uniform base + lane*16B), 16B per lane
__device__ __forceinline__ void gl16(const void* g, const void* l) {
  __builtin_amdgcn_global_load_lds(
      (const __attribute__((address_space(1))) unsigned int*)g,
      (__attribute__((address_space(3))) unsigned int*)l, 16, 0, 0);
}

// ---------------------------------------------------------------------------
// gather-split: Ah/Al[row][512] bf16 hi/lo of embed[seq[row]]
// ---------------------------------------------------------------------------
__global__ __launch_bounds__(256)
void gather_split(const int* __restrict__ seq, const float* __restrict__ embed,
                  ushort_t* __restrict__ Ah, ushort_t* __restrict__ Al)
{
  const int wid = threadIdx.x >> 6, lane = threadIdx.x & 63;
  const int row = blockIdx.x * 4 + wid;
  const float* src = embed + (size_t)seq[row] * 512 + lane * 8;
  const float4 a = *(const float4*)src;
  const float4 b = *(const float4*)(src + 4);
  u16x8 h, l;
  split8(a, b, h, l);
  *(u16x8*)(Ah + (size_t)row * 512 + lane * 8) = h;
  *(u16x8*)(Al + (size_t)row * 512 + lane * 8) = l;
}

// elementwise weight split (n8 = total_elems/8)
__global__ __launch_bounds__(256)
void split_w(const float* __restrict__ W, ushort_t* __restrict__ Wh,
             ushort_t* __restrict__ Wl, int n8)
{
  const int i = blockIdx.x * 256 + threadIdx.x;
  if (i >= n8) return;
  const float4 a = *(const float4*)(W + (size_t)i * 8);
  const float4 b = *(const float4*)(W + (size_t)i * 8 + 4);
  u16x8 h, l;
  split8(a, b, h, l);
  *(u16x8*)(Wh + (size_t)i * 8) = h;
  *(u16x8*)(Wl + (size_t)i * 8) = l;
}

// ---------------------------------------------------------------------------
// Split-bf16 MFMA GEMM as a virtual-K' (=3K) bf16 GEMM:
//   C = Ah.Bh^T + Al.Bh^T + Ah.Bl^T  ==  A'.B'^T with A'=[Ah|Al|Ah],
//   B'=[Bh|Bh|Bl] (third selected per K-tile by pointer).
// 256x256 tile, BK=32, 8 waves (2Mx4N), per-wave 128x64 via 8x4 16x16x32
// frags. 3-stage LDS (96KB) depth-2 prefetch, counted s_waitcnt vmcnt(4)
// + raw s_barrier (T3+T4), setprio around MFMA (T5). Chunk-XOR LDS swizzle
// (proven 0-conflict) applied via pre-swizzled global source (gl_lds dest
// stays linear).
// EPI 0: +bias, relu, store bf16 hi/lo.  EPI 1: +bias +embed[seq[row]],
// store f32.
// ---------------------------------------------------------------------------
template<int EPI>
__global__ __launch_bounds__(512, 1)
void gemm_pre(const ushort_t* __restrict__ Ah, const ushort_t* __restrict__ Al,
              const ushort_t* __restrict__ Bh, const ushort_t* __restrict__ Bl,
              const float* __restrict__ bias,
              const int* __restrict__ seq, const float* __restrict__ embed,
              ushort_t* __restrict__ Oh, ushort_t* __restrict__ Ol,
              float* __restrict__ Of,
              int N, int K)
{
  __shared__ __align__(16) ushort_t lds[3 * 16384];   // 3 stages x 32KB = 96KB
  const int tid = threadIdx.x;
  const int numN = N >> 8;
  int bid = blockIdx.x;
  {  // XCD-aware swizzle (grids are multiples of 8)
    const int chunk = gridDim.x >> 3;
    bid = (bid & 7) * chunk + (bid >> 3);
  }
  const int m0 = (bid / numN) << 8;
  const int n0 = (bid % numN) << 8;
  const int wid = tid >> 6, lane = tid & 63;
  const int wm = wid >> 2, wn = wid & 3;
  const int l16 = lane & 15, lkb = lane >> 4;

  const int tpt = K >> 5;        // K-tiles per third
  const int NT  = 3 * tpt;       // virtual K' tiles

  // staging geometry: per matrix-tile (256x32 bf16 = 16KB): rows r=0..255 of
  // 4 chunks x 16B; LDS chunk (r,cp) holds global chunk (r, cp^((r>>1)&3)).
  // Thread covers (j*512+tid) for j=0,1 -> r = j*128 + (tid>>2), cp = tid&3.
  const int rst = tid >> 2;                               // 0..127
  const int cu  = (((tid & 3) ^ ((rst >> 1) & 3)) << 3);  // swizzled col (u16)
  const size_t offA = (size_t)(m0 + rst) * (size_t)K + cu;
  const size_t offB = (size_t)(n0 + rst) * (size_t)K + cu;
  const size_t rowK128 = (size_t)128 * (size_t)K;
  ushort_t* const dbase = lds + (wid << 9);               // + sb*16384

  auto STAGE = [&](int tt, int sb) {
    const int th = (tt >= tpt) + (tt >= 2 * tpt);
    const size_t kb = (size_t)((tt - th * tpt) << 5);
    const ushort_t* As = ((th == 1) ? Al : Ah) + offA + kb;
    const ushort_t* Bs = ((th == 2) ? Bl : Bh) + offB + kb;
    ushort_t* d = dbase + sb * 16384;
    gl16(As,           d);
    gl16(As + rowK128, d + 4096);
    gl16(Bs,           d + 8192);
    gl16(Bs + rowK128, d + 12288);
  };

  // fragment read offsets (u16): row R, chunk lkb lives at chunk
  // lkb ^ ((R>>1)&3) = lkb ^ ((l16>>1)&3) (lane-constant).
  const int chf = ((lkb ^ ((l16 >> 1) & 3)) << 3);
  const int aBase = (wm * 128 + l16) * 32 + chf;          // A region
  const int bBase = 8192 + (wn * 64 + l16) * 32 + chf;    // B region

  f32x4 acc[8][4];
#pragma unroll
  for (int m = 0; m < 8; ++m)
#pragma unroll
    for (int n = 0; n < 4; ++n) acc[m][n] = (f32x4){0.f, 0.f, 0.f, 0.f};

  STAGE(0, 0);
  STAGE(1, 1);
  asm volatile("s_waitcnt vmcnt(4)" ::: "memory");   // tile 0 landed
  __builtin_amdgcn_s_barrier();
  __builtin_amdgcn_sched_barrier(0);

  int sb = 0;
  for (int t = 0; t < NT; ++t) {
    const int sb2 = (sb + 2 >= 3) ? (sb - 1) : (sb + 2);
    if (t + 2 < NT) STAGE(t + 2, sb2);   // depth-2 prefetch
    const ushort_t* base = lds + sb * 16384;
#pragma unroll
    for (int q = 0; q < 4; ++q) {        // quadrant phases
      const int qm = q >> 1, qn = q & 1;
      bf16x8 fa[4], fb[2];
#pragma unroll
      for (int mi = 0; mi < 4; ++mi)
        fa[mi] = *(const bf16x8*)(base + aBase + (qm * 4 + mi) * 512);
#pragma unroll
      for (int ni = 0; ni < 2; ++ni)
        fb[ni] = *(const bf16x8*)(base + bBase + (qn * 2 + ni) * 512);
      __builtin_amdgcn_s_setprio(1);
#pragma unroll
      for (int ni = 0; ni < 2; ++ni)
#pragma unroll
        for (int mi = 0; mi < 4; ++mi)
          acc[qm * 4 + mi][qn * 2 + ni] = __builtin_amdgcn_mfma_f32_16x16x32_bf16(
              fa[mi], fb[ni], acc[qm * 4 + mi][qn * 2 + ni], 0, 0, 0);
      __builtin_amdgcn_s_setprio(0);
    }
    if (t + 1 < NT) {
      if (t + 2 < NT) asm volatile("s_waitcnt vmcnt(4)" ::: "memory");
      else            asm volatile("s_waitcnt vmcnt(0)" ::: "memory");
      __builtin_amdgcn_s_barrier();
      __builtin_amdgcn_sched_barrier(0);
    }
    sb = (sb + 1 >= 3) ? 0 : sb + 1;
  }

  // epilogue: C/D frag layout col=lane&15, row=(lane>>4)*4+i
#pragma unroll
  for (int n = 0; n < 4; ++n) {
    const int col = n0 + wn * 64 + n * 16 + l16;
    const float bv = bias[col];
#pragma unroll
    for (int m = 0; m < 8; ++m) {
      const int rbase = m0 + wm * 128 + m * 16 + lkb * 4;
#pragma unroll
      for (int i = 0; i < 4; ++i) {
        const int row = rbase + i;
        float v = acc[m][n][i] + bv;
        if (EPI == 0) {
          v = fmaxf(v, 0.f);
          const ushort_t h = f2bf(v);
          Oh[(size_t)row * N + col] = h;
          Ol[(size_t)row * N + col] = f2bf(v - bf2f(h));
        } else {
          v += embed[(size_t)seq[row] * 512 + col];
          Of[(size_t)row * N + col] = v;
        }
      }
    }
  }
}

// in-place LayerNorm + fused gate score + L2 norm; one wave per 512-elem row
__global__ __launch_bounds__(256)
void lnscore_k(float* __restrict__ x, const float* __restrict__ g,
               const float* __restrict__ bt, const float* __restrict__ wg_w,
               const float* __restrict__ wg_b, float* __restrict__ scores,
               float* __restrict__ norms)
{
  const int wid = threadIdx.x >> 6, lane = threadIdx.x & 63;
  const int row = blockIdx.x * 4 + wid;
  float* xr = x + (size_t)row * 512;
  const float4 v0 = *(const float4*)(xr + lane*4);
  const float4 v1 = *(const float4*)(xr + 256 + lane*4);
  float s = v0.x+v0.y+v0.z+v0.w + v1.x+v1.y+v1.z+v1.w;
  s = wsum64(s);
  const float mu = s * (1.f/512.f);
  float ss = (v0.x-mu)*(v0.x-mu) + (v0.y-mu)*(v0.y-mu)
           + (v0.z-mu)*(v0.z-mu) + (v0.w-mu)*(v0.w-mu)
           + (v1.x-mu)*(v1.x-mu) + (v1.y-mu)*(v1.y-mu)
           + (v1.z-mu)*(v1.z-mu) + (v1.w-mu)*(v1.w-mu);
  ss = wsum64(ss);
  const float inv = 1.f / sqrtf(ss * (1.f/512.f) + 1e-5f);
  const float4 g0 = *(const float4*)(g + lane*4);
  const float4 g1 = *(const float4*)(g + 256 + lane*4);
  const float4 c0 = *(const float4*)(bt + lane*4);
  const float4 c1 = *(const float4*)(bt + 256 + lane*4);
  float4 o0, o1;
  o0.x = (v0.x-mu)*inv*g0.x + c0.x;  o0.y = (v0.y-mu)*inv*g0.y + c0.y;
  o0.z = (v0.z-mu)*inv*g0.z + c0.z;  o0.w = (v0.w-mu)*inv*g0.w + c0.w;
  o1.x = (v1.x-mu)*inv*g1.x + c1.x;  o1.y = (v1.y-mu)*inv*g1.y + c1.y;
  o1.z = (v1.z-mu)*inv*g1.z + c1.z;  o1.w = (v1.w-mu)*inv*g1.w + c1.w;
  *(float4*)(xr + lane*4) = o0;
  *(float4*)(xr + 256 + lane*4) = o1;

  const float4 q0 = *(const float4*)(wg_w + lane*4);
  const float4 q1 = *(const float4*)(wg_w + 256 + lane*4);
  float d = o0.x*q0.x + o0.y*q0.y + o0.z*q0.z + o0.w*q0.w
          + o1.x*q1.x + o1.y*q1.y + o1.z*q1.z + o1.w*q1.w;
  float n2 = o0.x*o0.x + o0.y*o0.y + o0.z*o0.z + o0.w*o0.w
           + o1.x*o1.x + o1.y*o1.y + o1.z*o1.z + o1.w*o1.w;
  d = wsum64(d); n2 = wsum64(n2);
  const int b = row >> 10, t = row & 1023;
  if (lane == 0 && t < 1021) {
    scores[b * 1021 + t] = d + wg_b[0];
    norms[b * 1021 + t] = sqrtf(n2);
  }
}

// ---------------------------------------------------------------------------
// Greedy score-ranked selection with cosine dedup; one block per batch row.
// ---------------------------------------------------------------------------
__global__ __launch_bounds__(256, 1)
void select_k(const float* __restrict__ hidden, const float* __restrict__ scores,
              const float* __restrict__ norms, int* __restrict__ selidx_g,
              int* __restrict__ selcnt_g)
{
  __shared__ __align__(16) ushort_t allH[128 * 520];     // 133120 B (keys alias)
  __shared__ ushort_t simS[64 * 128];
  __shared__ ushort_t sortedIdx[1024];
  __shared__ ushort_t selT[64];
  __shared__ ushort_t newPos[64];
  __shared__ int s_count, s_nacc;

  const int b = blockIdx.x, tid = threadIdx.x;
  const int wid = tid >> 6, lane = tid & 63;
  const int l16 = lane & 15, lkb = lane >> 4;

  // ---- phase 1: bitonic argsort by (-score, idx), stable
  unsigned long long* keys = (unsigned long long*)allH;
  for (int i = tid; i < 1024; i += 256) {
    const float s = (i < 1021) ? scores[b * 1021 + i] : -INFINITY;
    const unsigned u = __float_as_uint(s);
    const unsigned ms = (u & 0x80000000u) ? ~u : (u | 0x80000000u);
    keys[i] = ((unsigned long long)(~ms) << 32) | (unsigned)i;
  }
  __syncthreads();
  for (int k = 2; k <= 1024; k <<= 1) {
    for (int j = k >> 1; j > 0; j >>= 1) {
      for (int i = tid; i < 1024; i += 256) {
        const int ixj = i ^ j;
        if (ixj > i) {
          const unsigned long long a = keys[i], c = keys[ixj];
          const bool up = ((i & k) == 0);
          if ((a > c) == up) { keys[i] = c; keys[ixj] = a; }
        }
      }
      __syncthreads();
    }
  }
  for (int i = tid; i < 1024; i += 256)
    sortedIdx[i] = (ushort_t)(keys[i] & 0xffffu);
  if (tid == 0) s_count = 0;
  __syncthreads();

  // ---- phase 2: chunked greedy NMS
  int p = 0;
  while (true) {
    const int count = s_count;
    if (count >= 64 || p >= 1021) break;
    const int C = min(64, 1021 - p);

    {
      const int r = tid >> 2;
      const int seg = (tid & 3) * 128;
      if (r < C) {
        const int t = sortedIdx[p + r];
        const float rn = 1.f / fmaxf(norms[b * 1021 + t], 1e-12f);
        const float* src = hidden + ((size_t)b * 1024 + t) * 512 + seg;
        ushort_t* dst = allH + (64 + r) * 520 + seg;
#pragma unroll
        for (int u0 = 0; u0 < 128; u0 += 8) {
          const float4 x = *(const float4*)(src + u0);
          const float4 y = *(const float4*)(src + u0 + 4);
          u16x8 o;
          o[0] = f2bf(x.x * rn); o[1] = f2bf(x.y * rn);
          o[2] = f2bf(x.z * rn); o[3] = f2bf(x.w * rn);
          o[4] = f2bf(y.x * rn); o[5] = f2bf(y.y * rn);
          o[6] = f2bf(y.z * rn); o[7] = f2bf(y.w * rn);
          *(u16x8*)(dst + u0) = o;
        }
      }
    }
    __syncthreads();

    {
      f32x4 acc[8];
#pragma unroll
      for (int t = 0; t < 8; ++t) acc[t] = (f32x4){0.f, 0.f, 0.f, 0.f};
      const ushort_t* Abase = allH + (64 + (wid << 4) + l16) * 520;
#pragma unroll
      for (int ks = 0; ks < 16; ++ks) {
        const bf16x8 a = *(const bf16x8*)(Abase + ks * 32 + lkb * 8);
#pragma unroll
        for (int t = 0; t < 8; ++t) {
          const bf16x8 bb = *(const bf16x8*)(allH + ((t << 4) + l16) * 520 + ks * 32 + lkb * 8);
          acc[t] = __builtin_amdgcn_mfma_f32_16x16x32_bf16(a, bb, acc[t], 0, 0, 0);
        }
      }
#pragma unroll
      for (int t = 0; t < 8; ++t)
#pragma unroll
        for (int ii = 0; ii < 4; ++ii) {
          const int ri = (wid << 4) + lkb * 4 + ii;
          simS[ri * 128 + (t << 4) + l16] = f2bf(acc[t][ii]);
        }
    }
    __syncthreads();

    if (wid == 0) {
      unsigned long long accMask = 0ull;
      int nacc = 0;
      for (int i = 0; i < C; ++i) {
        float v = -INFINITY;
        if (lane < count) v = bf2f(simS[i * 128 + lane]);
        if ((accMask >> lane) & 1ull) v = fmaxf(v, bf2f(simS[i * 128 + 64 + lane]));
#pragma unroll
        for (int off = 32; off > 0; off >>= 1) v = fmaxf(v, __shfl_xor(v, off, 64));
        const int total = count + nacc;
        const bool ok = (total == 0) || (v <= 0.8f);
        if (total < 64 && ok) {
          if (lane == 0) { selT[total] = sortedIdx[p + i]; newPos[nacc] = (ushort_t)i; }
          accMask |= (1ull << i);
          ++nacc;
          if (total + 1 == 64) break;
        }
      }
      if (lane == 0) { s_nacc = nacc; s_count = count + nacc; }
    }
    __syncthreads();

    {
      const int nacc = s_nacc;
      for (int a = wid; a < nacc; a += 4) {
        const int srcrow = 64 + (int)newPos[a];
        const int dstrow = count + a;
        const u16x8 val = *(const u16x8*)(allH + srcrow * 520 + lane * 8);
        *(u16x8*)(allH + dstrow * 520 + lane * 8) = val;
      }
    }
    p += C;
    __syncthreads();
  }

  __syncthreads();
  if (tid < 64) selidx_g[b * 64 + tid] = (tid < s_count) ? (int)selT[tid] : 0;
  if (tid == 0) selcnt_g[b] = s_count;
}

// q = hidden[:, T-2, :] @ q_w^T + q_b ; one wave per output element
__global__ __launch_bounds__(256)
void q_k(const float* __restrict__ hidden, const float* __restrict__ q_w,
         const float* __restrict__ q_b, float* __restrict__ qv)
{
  const int wid = threadIdx.x >> 6, lane = threadIdx.x & 63;
  const int o = blockIdx.x * 4 + wid;
  const int b = o >> 9, n = o & 511;
  const float* hr = hidden + ((size_t)b*1024 + 1022) * 512;
  const float* wr = q_w + (size_t)n * 512;
  const float4 h0 = *(const float4*)(hr + lane*4);
  const float4 h1 = *(const float4*)(hr + 256 + lane*4);
  const float4 w0 = *(const float4*)(wr + lane*4);
  const float4 w1 = *(const float4*)(wr + 256 + lane*4);
  float d = h0.x*w0.x + h0.y*w0.y + h0.z*w0.z + h0.w*w0.w
          + h1.x*w1.x + h1.y*w1.y + h1.z*w1.z + h1.w*w1.w;
  d = wsum64(d);
  if (lane == 0) qv[o] = d + q_b[n];
}

// masked softmax attention over selected memory; one block per batch
__global__ __launch_bounds__(256)
void attn_k(const float* __restrict__ hidden, const float* __restrict__ qv,
            const int* __restrict__ selidx_g, const int* __restrict__ selcnt_g,
            float* __restrict__ ctx)
{
  const int b = blockIdx.x, tid = threadIdx.x;
  const int wid = tid >> 6, lane = tid & 63;
  __shared__ float qs[512];
  __shared__ int sidx[64];
  __shared__ float sv[64];
  __shared__ float av[64];
  const int count = selcnt_g[b];
  for (int i = tid; i < 512; i += 256) qs[i] = qv[b*512 + i];
  if (tid < 64) sidx[tid] = selidx_g[b*64 + tid];
  __syncthreads();
  for (int m = wid; m < 64; m += 4) {
    float sval = -1e9f;
    if (m < count) {
      const float* hr = hidden + ((size_t)b*1024 + sidx[m]) * 512;
      const float4 a0 = *(const float4*)(hr + lane*4);
      const float4 a1 = *(const float4*)(hr + 256 + lane*4);
      const float4 q0 = *(const float4*)(&qs[lane*4]);
      const float4 q1 = *(const float4*)(&qs[256 + lane*4]);
      float d = a0.x*q0.x + a0.y*q0.y + a0.z*q0.z + a0.w*q0.w
              + a1.x*q1.x + a1.y*q1.y + a1.z*q1.z + a1.w*q1.w;
      d = wsum64(d);
      sval = d;
    }
    if (lane == 0) sv[m] = sval;
  }
  __syncthreads();
  if (tid < 64) {
    const float v = sv[tid];
    float mx = v;
#pragma unroll
    for (int off = 32; off > 0; off >>= 1) mx = fmaxf(mx, __shfl_xor(mx, off, 64));
    const float e = expf(v - mx);
    float ssum = e;
#pragma unroll
    for (int off = 32; off > 0; off >>= 1) ssum += __shfl_xor(ssum, off, 64);
    av[tid] = e / ssum;
  }
  __syncthreads();
  for (int n = tid; n < 512; n += 256) {
    float a = 0.f;
    for (int m = 0; m < count; ++m)
      a += av[m] * hidden[((size_t)b*1024 + sidx[m]) * 512 + n];
    ctx[b*512 + n] = a;
  }
}

// out = ctx @ out_w^T + out_b ; 16 vocab rows x all 32 batches per block
__global__ __launch_bounds__(256)
void out_k(const float* __restrict__ ctx, const float* __restrict__ out_w,
           const float* __restrict__ out_b, float* __restrict__ out)
{
  __shared__ float ctxT[512][33];
  const int tid = threadIdx.x;
  const int v0 = blockIdx.x * 16;
  for (int i = tid; i < 4096; i += 256) {
    const int bb = i & 31;
    const int k4 = (i >> 5) * 4;
    const float4 v = *(const float4*)(ctx + (size_t)bb * 512 + k4);
    ctxT[k4+0][bb] = v.x; ctxT[k4+1][bb] = v.y;
    ctxT[k4+2][bb] = v.z; ctxT[k4+3][bb] = v.w;
  }
  __syncthreads();
  const int bb = tid & 31;       // batch
  const int ty = tid >> 5;       // 0..7
#pragma unroll
  for (int vi = 0; vi < 2; ++vi) {
    const int v = v0 + vi * 8 + ty;
    const float* wr = out_w + (size_t)v * 512;
    float acc = 0.f;
#pragma unroll 4
    for (int k = 0; k < 512; k += 4) {
      const float4 w4 = *(const float4*)(wr + k);
      acc = fmaf(w4.x, ctxT[k+0][bb], acc);
      acc = fmaf(w4.y, ctxT[k+1][bb], acc);
      acc = fmaf(w4.z, ctxT[k+2][bb], acc);
      acc = fmaf(w4.w, ctxT[k+3][bb], acc);
    }
    out[(size_t)bb * 32000 + v] = acc + out_b[v];
  }
}

extern "C" void kernel_launch(void* const* d_in, const int* in_sizes, int n_in,
                              void* d_out, int out_size, void* d_ws, size_t ws_size,
                              hipStream_t stream)
{
  const int*   seq   = (const int*)d_in[0];
  const float* embed = (const float*)d_in[1];
  const float* w1    = (const float*)d_in[2];
  const float* b1    = (const float*)d_in[3];
  const float* w2    = (const float*)d_in[4];
  const float* b2    = (const float*)d_in[5];
  const float* ln_g  = (const float*)d_in[6];
  const float* ln_b  = (const float*)d_in[7];
  const float* wg_w  = (const float*)d_in[8];
  const float* wg_b  = (const float*)d_in[9];
  const float* q_w   = (const float*)d_in[10];
  const float* q_b   = (const float*)d_in[11];
  const float* out_w = (const float*)d_in[12];
  const float* out_b = (const float*)d_in[13];
  float* out = (float*)d_out;

  char* ws = (char*)d_ws;
  size_t off = 0;
  auto alloc = [&](size_t bytes) {
    void* p = ws + off;
    off += (bytes + 255) & ~(size_t)255;
    return p;
  };
  // Ahid/Alid (pre-split gathered hidden input) alias xbuf: dead after FF1.
  void* xA = alloc((size_t)32768 * 512 * 4);            // 67 MB
  ushort_t* Ahid = (ushort_t*)xA;
  ushort_t* Alid = Ahid + (size_t)32768 * 512;
  float* xbuf = (float*)xA;
  ushort_t* ff1h = (ushort_t*)alloc((size_t)32768 * 1024 * 2);  // 67 MB
  ushort_t* ff1l = (ushort_t*)alloc((size_t)32768 * 1024 * 2);  // 67 MB
  ushort_t* w1h = (ushort_t*)alloc((size_t)1024 * 512 * 2);
  ushort_t* w1l = (ushort_t*)alloc((size_t)1024 * 512 * 2);
  ushort_t* w2h = (ushort_t*)alloc((size_t)512 * 1024 * 2);
  ushort_t* w2l = (ushort_t*)alloc((size_t)512 * 1024 * 2);
  float* scores = (float*)alloc((size_t)32 * 1021 * 4);
  float* norms  = (float*)alloc((size_t)32 * 1021 * 4);
  int*   selidx = (int*)alloc((size_t)32 * 64 * 4);
  int*   selcnt = (int*)alloc((size_t)32 * 4);
  float* qbuf   = (float*)alloc((size_t)32 * 512 * 4);
  float* ctxb   = (float*)alloc((size_t)32 * 512 * 4);

  // pre-split passes
  gather_split<<<8192, 256, 0, stream>>>(seq, embed, Ahid, Alid);
  split_w<<<256, 256, 0, stream>>>(w1, w1h, w1l, 65536);
  split_w<<<256, 256, 0, stream>>>(w2, w2h, w2l, 65536);

  // FF1: relu(h @ w1^T + b1) -> ff1 hi/lo bf16   [32768,1024]
  gemm_pre<0><<<512, 512, 0, stream>>>(Ahid, Alid, w1h, w1l, b1,
                                       nullptr, nullptr, ff1h, ff1l, nullptr,
                                       1024, 512);
  // FF2: ff1 @ w2^T + b2 + embed[seq] -> xbuf f32 [32768,512]
  gemm_pre<1><<<256, 512, 0, stream>>>(ff1h, ff1l, w2h, w2l, b2,
                                       seq, embed, nullptr, nullptr, xbuf,
                                       512, 1024);
  // LayerNorm in place + fused scores/norms
  lnscore_k<<<8192, 256, 0, stream>>>(xbuf, ln_g, ln_b, wg_w, wg_b, scores, norms);
  // greedy dedup selection
  select_k<<<32, 256, 0, stream>>>(xbuf, scores, norms, selidx, selcnt);
  // q projection for query row (t = 1022)
  q_k<<<4096, 256, 0, stream>>>(xbuf, q_w, q_b, qbuf);
  // attention over selected memory -> ctx
  attn_k<<<32, 256, 0, stream>>>(xbuf, qbuf, selidx, selcnt, ctxb);
  // final vocab projection
  out_k<<<2000, 256, 0, stream>>>(ctxb, out_w, out_b, out);
}

// Round 6
// 482.071 us; speedup vs baseline: 1.1091x; 1.1091x over previous
//
#include <hip/hip_runtime.h>
#include <math.h>

typedef unsigned short ushort_t;
typedef short bf16x8 __attribute__((ext_vector_type(8)));
typedef unsigned short u16x8 __attribute__((ext_vector_type(8)));
typedef float f32x4 __attribute__((ext_vector_type(4)));

__device__ __forceinline__ float wsum64(float v) {
#pragma unroll
  for (int off = 32; off > 0; off >>= 1) v += __shfl_xor(v, off, 64);
  return v;
}

__device__ __forceinline__ ushort_t f2bf(float x) {   // RNE f32->bf16
  unsigned u = __float_as_uint(x);
  return (ushort_t)((u + 0x7fffu + ((u >> 16) & 1u)) >> 16);
}
__device__ __forceinline__ float bf2f(ushort_t h) {
  return __uint_as_float(((unsigned)h) << 16);
}

__device__ __forceinline__ void split8(const float4 a, const float4 b,
                                       u16x8& h, u16x8& l) {
  h[0]=f2bf(a.x); l[0]=f2bf(a.x-bf2f(h[0]));
  h[1]=f2bf(a.y); l[1]=f2bf(a.y-bf2f(h[1]));
  h[2]=f2bf(a.z); l[2]=f2bf(a.z-bf2f(h[2]));
  h[3]=f2bf(a.w); l[3]=f2bf(a.w-bf2f(h[3]));
  h[4]=f2bf(b.x); l[4]=f2bf(b.x-bf2f(h[4]));
  h[5]=f2bf(b.y); l[5]=f2bf(b.y-bf2f(h[5]));
  h[6]=f2bf(b.z); l[6]=f2bf(b.z-bf2f(h[6]));
  h[7]=f2bf(b.w); l[7]=f2bf(b.w-bf2f(h[7]));
}

// async global(per-lane) -> LDS(wave-uniform base + lane*16B), 16B per lane
__device__ __forceinline__ void gl16(const void* g, const void* l) {
  __builtin_amdgcn_global_load_lds(
      (const __attribute__((address_space(1))) unsigned int*)g,
      (__attribute__((address_space(3))) unsigned int*)l, 16, 0, 0);
}

#define SBAR __builtin_amdgcn_sched_barrier(0)
#define BARRIER __builtin_amdgcn_s_barrier()
#define LGKM0 asm volatile("s_waitcnt lgkmcnt(0)" ::: "memory")
#define VMC6 asm volatile("s_waitcnt vmcnt(6)" ::: "memory")
#define VMC0 asm volatile("s_waitcnt vmcnt(0)" ::: "memory")

// ---------------------------------------------------------------------------
// gather-split: Ah/Al[row][512] bf16 hi/lo of embed[seq[row]]
// ---------------------------------------------------------------------------
__global__ __launch_bounds__(256)
void gather_split(const int* __restrict__ seq, const float* __restrict__ embed,
                  ushort_t* __restrict__ Ah, ushort_t* __restrict__ Al)
{
  const int wid = threadIdx.x >> 6, lane = threadIdx.x & 63;
  const int row = blockIdx.x * 4 + wid;
  const float* src = embed + (size_t)seq[row] * 512 + lane * 8;
  const float4 a = *(const float4*)src;
  const float4 b = *(const float4*)(src + 4);
  u16x8 h, l;
  split8(a, b, h, l);
  *(u16x8*)(Ah + (size_t)row * 512 + lane * 8) = h;
  *(u16x8*)(Al + (size_t)row * 512 + lane * 8) = l;
}

// elementwise weight split (n8 = total_elems/8)
__global__ __launch_bounds__(256)
void split_w(const float* __restrict__ W, ushort_t* __restrict__ Wh,
             ushort_t* __restrict__ Wl, int n8)
{
  const int i = blockIdx.x * 256 + threadIdx.x;
  if (i >= n8) return;
  const float4 a = *(const float4*)(W + (size_t)i * 8);
  const float4 b = *(const float4*)(W + (size_t)i * 8 + 4);
  u16x8 h, l;
  split8(a, b, h, l);
  *(u16x8*)(Wh + (size_t)i * 8) = h;
  *(u16x8*)(Wl + (size_t)i * 8) = l;
}

// ---------------------------------------------------------------------------
// Split-bf16 MFMA GEMM, 8-phase schedule (T3+T4+T5, m201 template).
//   C = Ah.Bh^T + Al.Bh^T + Ah.Bl^T  as virtual K'=3K tiles of BK=64:
//   tile thirds: A'=[Ah|Al|Ah], B'=[Bh|Bh|Bl].
// 256x256 tile, 8 waves (2Mx4N), per-wave 128x64 = acc[8][4].
// LDS 128KB = 2 dbuf x (A 32KB + B 32KB); even tiles dbuf0, odd dbuf1.
// Per K-tile 4 C-quadrant phases (qm,qn) = (00),(01),(10),(11); 16 MFMA each.
// Region-permuted LDS: A lrow = qm*128+wm*64+...; B lrow = qn*128+wn*32+...
// so each stage half (h = qm/qn set) is contiguous; chunk XOR swizzle
// (lrow&7) applied via pre-swizzled global source -> 2-way reads (free).
// Stage stream: ph0:A1(t2i+1) ph1:B1(t2i+1) ph2:A0(t2i+2) ph3:B0 ph4:A1
// ph5:B1 ph6:A0(t2i+3) ph7:B0. vmcnt(6) at ph0/ph4 (3 half-tiles in flight);
// last-iter ph4 uses vmcnt(0) (only 4 loads outstanding -> vmcnt(6) no-op).
// EPI 0: +bias, relu, split -> Oh/Ol via per-wave LDS bounce (coalesced 8B).
// EPI 1: +bias + embed[seq[row]] resid -> f32 (already coalesced).
// ---------------------------------------------------------------------------
template<int EPI>
__global__ __launch_bounds__(512, 1)
void gemm8(const ushort_t* __restrict__ Ah, const ushort_t* __restrict__ Al,
           const ushort_t* __restrict__ Bh, const ushort_t* __restrict__ Bl,
           const float* __restrict__ bias,
           const int* __restrict__ seq, const float* __restrict__ embed,
           ushort_t* __restrict__ Oh, ushort_t* __restrict__ Ol,
           float* __restrict__ Of, int N, int K)
{
  __shared__ __align__(16) ushort_t lds[65536];   // 128 KB
  const int tid = threadIdx.x;
  const int numN = N >> 8;
  int bid = blockIdx.x;
  {  // XCD-aware swizzle (grids are multiples of 8)
    const int chunk = gridDim.x >> 3;
    bid = (bid & 7) * chunk + (bid >> 3);
  }
  const int m0 = (bid / numN) << 8;
  const int n0 = (bid % numN) << 8;
  const int wid = tid >> 6, lane = tid & 63;
  const int wm = wid >> 2, wn = wid & 3;
  const int l16 = lane & 15, lkb = lane >> 4;

  const int tpt = K >> 6;       // real-K tiles per third
  const int NT  = 3 * tpt;      // virtual tiles
  const int NI  = NT >> 1;      // iterations (2 tiles each)

  // ---- staging precompute: this thread's 2 chunks per half h
  int srcA[2][2], srcB[2][2];   // [h][j] element offsets (row*K + col)
  {
    const int c0 = wid * 64 + lane;
#pragma unroll
    for (int j = 0; j < 2; ++j) {
      const int c = c0 + j * 512;
      const int lr = c >> 3, ch = c & 7;
#pragma unroll
      for (int h = 0; h < 2; ++h) {
        const int lrow = h * 128 + lr;
        const int col = ((ch ^ (lrow & 7)) << 3);
        const int rA = (lrow & 63) | ((lrow & 64) << 1) | ((lrow & 128) >> 1);
        const int rB = ((lrow >> 5) & 3) * 64 + (lrow >> 7) * 32 + (lrow & 31);
        srcA[h][j] = rA * K + col;
        srcB[h][j] = rB * K + col;
      }
    }
  }
  const size_t aRow0 = (size_t)m0 * K;
  const size_t bRow0 = (size_t)n0 * K;

  auto stageH = [&](int ts, int matH) {   // matH: 0=(A,h0) 1=(B,h0) 2=(A,h1) 3=(B,h1)
    const int mat = matH & 1, h = matH >> 1;
    const int th = (ts >= tpt) + (ts >= 2 * tpt);
    const int kb = (ts - th * tpt) << 6;
    ushort_t* dst = lds + ((ts & 1) << 15) + mat * 16384 + h * 8192 + wid * 512;
    if (mat == 0) {
      const ushort_t* bp = ((th == 1) ? Al : Ah) + aRow0 + kb;
      gl16(bp + srcA[h][0], dst);
      gl16(bp + srcA[h][1], dst + 4096);
    } else {
      const ushort_t* bp = ((th == 2) ? Bl : Bh) + bRow0 + kb;
      gl16(bp + srcB[h][0], dst);
      gl16(bp + srcB[h][1], dst + 4096);
    }
  };

  // ---- fragment addressing
  const int swz = l16 & 7;
  int cSwz[2];
  cSwz[0] = ((lkb ^ swz) << 3);
  cSwz[1] = (((4 + lkb) ^ swz) << 3);
  const int aLane = (wm * 64 + l16) * 64;          // + d + qm*8192 + m*1024 + cSwz
  const int bLane = 16384 + (wn * 32 + l16) * 64;  // + d + qn*8192 + nf*1024 + cSwz

  bf16x8 fa[4][2], fb0[2][2], fb1[2][2];
  f32x4 acc[8][4];
#pragma unroll
  for (int m = 0; m < 8; ++m)
#pragma unroll
    for (int n = 0; n < 4; ++n) acc[m][n] = (f32x4){0.f, 0.f, 0.f, 0.f};

  auto loadA = [&](int doff, int qm) {
#pragma unroll
    for (int m = 0; m < 4; ++m)
#pragma unroll
      for (int ks = 0; ks < 2; ++ks)
        fa[m][ks] = *(const bf16x8*)(lds + doff + qm * 8192 + aLane + m * 1024 + cSwz[ks]);
  };
  auto loadB = [&](int doff, int qn, bf16x8 (*fb)[2]) {
#pragma unroll
    for (int nf = 0; nf < 2; ++nf)
#pragma unroll
      for (int ks = 0; ks < 2; ++ks)
        fb[nf][ks] = *(const bf16x8*)(lds + doff + qn * 8192 + bLane + nf * 1024 + cSwz[ks]);
  };
  auto mfmaQ = [&](int qm, int qn, bf16x8 (*fb)[2]) {
    __builtin_amdgcn_s_setprio(1);
#pragma unroll
    for (int m = 0; m < 4; ++m)
#pragma unroll
      for (int nf = 0; nf < 2; ++nf) {
        f32x4 a = acc[qm * 4 + m][qn * 2 + nf];
        a = __builtin_amdgcn_mfma_f32_16x16x32_bf16(fa[m][0], fb[nf][0], a, 0, 0, 0);
        a = __builtin_amdgcn_mfma_f32_16x16x32_bf16(fa[m][1], fb[nf][1], a, 0, 0, 0);
        acc[qm * 4 + m][qn * 2 + nf] = a;
      }
    __builtin_amdgcn_s_setprio(0);
  };

  // ---- prologue: tile0 fully + tile1 halves A0,B0 (steady-state pattern)
  stageH(0, 0); stageH(0, 1); stageH(0, 2); stageH(0, 3);
  stageH(1, 0); stageH(1, 1);
  asm volatile("s_waitcnt vmcnt(4)" ::: "memory");
  BARRIER; SBAR;

  for (int i = 0; i < NI; ++i) {
    const int t1 = 2 * i + 1, t2 = 2 * i + 2, t3 = 2 * i + 3;
    const bool more = (i + 1 < NI);
    // p0 (tile 2i, dbuf0, q00)
    loadA(0, 0); loadB(0, 0, fb0); stageH(t1, 2); SBAR; VMC6;
    BARRIER; LGKM0; SBAR; mfmaQ(0, 0, fb0); BARRIER;
    // p1 (q01)
    loadB(0, 1, fb1); stageH(t1, 3); SBAR;
    BARRIER; LGKM0; SBAR; mfmaQ(0, 1, fb1); BARRIER;
    // p2 (q10)
    loadA(0, 1); if (more) stageH(t2, 0); SBAR;
    BARRIER; LGKM0; SBAR; mfmaQ(1, 0, fb0); BARRIER;
    // p3 (q11)
    if (more) stageH(t2, 1); SBAR;
    BARRIER; LGKM0; SBAR; mfmaQ(1, 1, fb1); BARRIER;
    // p4 (tile 2i+1, dbuf1, q00)
    loadA(32768, 0); loadB(32768, 0, fb0);
    if (more) { stageH(t2, 2); SBAR; VMC6; }
    else      { SBAR; VMC0; }              // tail: drain p0/p1 stages (only 4 out)
    BARRIER; LGKM0; SBAR; mfmaQ(0, 0, fb0); BARRIER;
    // p5 (q01)
    loadB(32768, 1, fb1); if (more) stageH(t2, 3); SBAR;
    BARRIER; LGKM0; SBAR; mfmaQ(0, 1, fb1); BARRIER;
    // p6 (q10)
    loadA(32768, 1); if (more) stageH(t3, 0); SBAR;
    BARRIER; LGKM0; SBAR; mfmaQ(1, 0, fb0); BARRIER;
    // p7 (q11)
    if (more) stageH(t3, 1); SBAR;
    BARRIER; LGKM0; SBAR; mfmaQ(1, 1, fb1); BARRIER;
  }

  // ---- epilogue (acc[m'][n']: row = wm*128+m'*16+lkb*4+i, col = wn*64+n'*16+l16)
  if (EPI == 0) {
    // per-wave LDS bounce -> coalesced 8B stores of hi/lo planes
    unsigned* pw = (unsigned*)lds + wid * 4096;   // 16KB per wave (LDS free now)
    float bv[4];
#pragma unroll
    for (int n = 0; n < 4; ++n) bv[n] = bias[n0 + wn * 64 + n * 16 + l16];
#pragma unroll
    for (int half = 0; half < 2; ++half) {
#pragma unroll
      for (int m = 0; m < 4; ++m) {
        const int mg = half * 4 + m;
#pragma unroll
        for (int n = 0; n < 4; ++n)
#pragma unroll
          for (int i = 0; i < 4; ++i) {
            float v = fmaxf(acc[mg][n][i] + bv[n], 0.f);
            const ushort_t h = f2bf(v);
            const ushort_t l = f2bf(v - bf2f(h));
            const int row = m * 16 + lkb * 4 + i;
            pw[row * 64 + n * 16 + l16] = ((unsigned)h << 16) | l;
          }
      }
#pragma unroll
      for (int p = 0; p < 16; ++p) {
        const int idx = p * 256 + lane * 4;
        const int row = idx >> 6, col = idx & 63;
        const uint4 w = *(const uint4*)(pw + idx);
        ushort4 hs, ls;
        hs.x = (ushort_t)(w.x >> 16); ls.x = (ushort_t)(w.x & 0xffffu);
        hs.y = (ushort_t)(w.y >> 16); ls.y = (ushort_t)(w.y & 0xffffu);
        hs.z = (ushort_t)(w.z >> 16); ls.z = (ushort_t)(w.z & 0xffffu);
        hs.w = (ushort_t)(w.w >> 16); ls.w = (ushort_t)(w.w & 0xffffu);
        const size_t go = (size_t)(m0 + wm * 128 + half * 64 + row) * N
                          + (n0 + wn * 64 + col);
        *(ushort4*)(Oh + go) = hs;
        *(ushort4*)(Ol + go) = ls;
      }
    }
  } else {
#pragma unroll
    for (int n = 0; n < 4; ++n) {
      const int col = n0 + wn * 64 + n * 16 + l16;
      const float bvv = bias[col];
#pragma unroll
      for (int m = 0; m < 8; ++m) {
        const int rbase = m0 + wm * 128 + m * 16 + lkb * 4;
#pragma unroll
        for (int i = 0; i < 4; ++i) {
          const int row = rbase + i;
          float v = acc[m][n][i] + bvv;
          v += embed[(size_t)seq[row] * 512 + col];
          Of[(size_t)row * N + col] = v;
        }
      }
    }
  }
}

// in-place LayerNorm + fused gate score + L2 norm; one wave per 512-elem row
__global__ __launch_bounds__(256)
void lnscore_k(float* __restrict__ x, const float* __restrict__ g,
               const float* __restrict__ bt, const float* __restrict__ wg_w,
               const float* __restrict__ wg_b, float* __restrict__ scores,
               float* __restrict__ norms)
{
  const int wid = threadIdx.x >> 6, lane = threadIdx.x & 63;
  const int row = blockIdx.x * 4 + wid;
  float* xr = x + (size_t)row * 512;
  const float4 v0 = *(const float4*)(xr + lane*4);
  const float4 v1 = *(const float4*)(xr + 256 + lane*4);
  float s = v0.x+v0.y+v0.z+v0.w + v1.x+v1.y+v1.z+v1.w;
  s = wsum64(s);
  const float mu = s * (1.f/512.f);
  float ss = (v0.x-mu)*(v0.x-mu) + (v0.y-mu)*(v0.y-mu)
           + (v0.z-mu)*(v0.z-mu) + (v0.w-mu)*(v0.w-mu)
           + (v1.x-mu)*(v1.x-mu) + (v1.y-mu)*(v1.y-mu)
           + (v1.z-mu)*(v1.z-mu) + (v1.w-mu)*(v1.w-mu);
  ss = wsum64(ss);
  const float inv = 1.f / sqrtf(ss * (1.f/512.f) + 1e-5f);
  const float4 g0 = *(const float4*)(g + lane*4);
  const float4 g1 = *(const float4*)(g + 256 + lane*4);
  const float4 c0 = *(const float4*)(bt + lane*4);
  const float4 c1 = *(const float4*)(bt + 256 + lane*4);
  float4 o0, o1;
  o0.x = (v0.x-mu)*inv*g0.x + c0.x;  o0.y = (v0.y-mu)*inv*g0.y + c0.y;
  o0.z = (v0.z-mu)*inv*g0.z + c0.z;  o0.w = (v0.w-mu)*inv*g0.w + c0.w;
  o1.x = (v1.x-mu)*inv*g1.x + c1.x;  o1.y = (v1.y-mu)*inv*g1.y + c1.y;
  o1.z = (v1.z-mu)*inv*g1.z + c1.z;  o1.w = (v1.w-mu)*inv*g1.w + c1.w;
  *(float4*)(xr + lane*4) = o0;
  *(float4*)(xr + 256 + lane*4) = o1;

  const float4 q0 = *(const float4*)(wg_w + lane*4);
  const float4 q1 = *(const float4*)(wg_w + 256 + lane*4);
  float d = o0.x*q0.x + o0.y*q0.y + o0.z*q0.z + o0.w*q0.w
          + o1.x*q1.x + o1.y*q1.y + o1.z*q1.z + o1.w*q1.w;
  float n2 = o0.x*o0.x + o0.y*o0.y + o0.z*o0.z + o0.w*o0.w
           + o1.x*o1.x + o1.y*o1.y + o1.z*o1.z + o1.w*o1.w;
  d = wsum64(d); n2 = wsum64(n2);
  const int b = row >> 10, t = row & 1023;
  if (lane == 0 && t < 1021) {
    scores[b * 1021 + t] = d + wg_b[0];
    norms[b * 1021 + t] = sqrtf(n2);
  }
}

// ---------------------------------------------------------------------------
// Greedy score-ranked selection with cosine dedup; one block per batch row.
// ---------------------------------------------------------------------------
__global__ __launch_bounds__(256, 1)
void select_k(const float* __restrict__ hidden, const float* __restrict__ scores,
              const float* __restrict__ norms, int* __restrict__ selidx_g,
              int* __restrict__ selcnt_g)
{
  __shared__ __align__(16) ushort_t allH[128 * 520];     // 133120 B (keys alias)
  __shared__ ushort_t simS[64 * 128];
  __shared__ ushort_t sortedIdx[1024];
  __shared__ ushort_t selT[64];
  __shared__ ushort_t newPos[64];
  __shared__ int s_count, s_nacc;

  const int b = blockIdx.x, tid = threadIdx.x;
  const int wid = tid >> 6, lane = tid & 63;
  const int l16 = lane & 15, lkb = lane >> 4;

  // ---- phase 1: bitonic argsort by (-score, idx), stable
  unsigned long long* keys = (unsigned long long*)allH;
  for (int i = tid; i < 1024; i += 256) {
    const float s = (i < 1021) ? scores[b * 1021 + i] : -INFINITY;
    const unsigned u = __float_as_uint(s);
    const unsigned ms = (u & 0x80000000u) ? ~u : (u | 0x80000000u);
    keys[i] = ((unsigned long long)(~ms) << 32) | (unsigned)i;
  }
  __syncthreads();
  for (int k = 2; k <= 1024; k <<= 1) {
    for (int j = k >> 1; j > 0; j >>= 1) {
      for (int i = tid; i < 1024; i += 256) {
        const int ixj = i ^ j;
        if (ixj > i) {
          const unsigned long long a = keys[i], c = keys[ixj];
          const bool up = ((i & k) == 0);
          if ((a > c) == up) { keys[i] = c; keys[ixj] = a; }
        }
      }
      __syncthreads();
    }
  }
  for (int i = tid; i < 1024; i += 256)
    sortedIdx[i] = (ushort_t)(keys[i] & 0xffffu);
  if (tid == 0) s_count = 0;
  __syncthreads();

  // ---- phase 2: chunked greedy NMS
  int p = 0;
  while (true) {
    const int count = s_count;
    if (count >= 64 || p >= 1021) break;
    const int C = min(64, 1021 - p);

    {
      const int r = tid >> 2;
      const int seg = (tid & 3) * 128;
      if (r < C) {
        const int t = sortedIdx[p + r];
        const float rn = 1.f / fmaxf(norms[b * 1021 + t], 1e-12f);
        const float* src = hidden + ((size_t)b * 1024 + t) * 512 + seg;
        ushort_t* dst = allH + (64 + r) * 520 + seg;
#pragma unroll
        for (int u0 = 0; u0 < 128; u0 += 8) {
          const float4 x = *(const float4*)(src + u0);
          const float4 y = *(const float4*)(src + u0 + 4);
          u16x8 o;
          o[0] = f2bf(x.x * rn); o[1] = f2bf(x.y * rn);
          o[2] = f2bf(x.z * rn); o[3] = f2bf(x.w * rn);
          o[4] = f2bf(y.x * rn); o[5] = f2bf(y.y * rn);
          o[6] = f2bf(y.z * rn); o[7] = f2bf(y.w * rn);
          *(u16x8*)(dst + u0) = o;
        }
      }
    }
    __syncthreads();

    {
      f32x4 acc[8];
#pragma unroll
      for (int t = 0; t < 8; ++t) acc[t] = (f32x4){0.f, 0.f, 0.f, 0.f};
      const ushort_t* Abase = allH + (64 + (wid << 4) + l16) * 520;
#pragma unroll
      for (int ks = 0; ks < 16; ++ks) {
        const bf16x8 a = *(const bf16x8*)(Abase + ks * 32 + lkb * 8);
#pragma unroll
        for (int t = 0; t < 8; ++t) {
          const bf16x8 bb = *(const bf16x8*)(allH + ((t << 4) + l16) * 520 + ks * 32 + lkb * 8);
          acc[t] = __builtin_amdgcn_mfma_f32_16x16x32_bf16(a, bb, acc[t], 0, 0, 0);
        }
      }
#pragma unroll
      for (int t = 0; t < 8; ++t)
#pragma unroll
        for (int ii = 0; ii < 4; ++ii) {
          const int ri = (wid << 4) + lkb * 4 + ii;
          simS[ri * 128 + (t << 4) + l16] = f2bf(acc[t][ii]);
        }
    }
    __syncthreads();

    if (wid == 0) {
      unsigned long long accMask = 0ull;
      int nacc = 0;
      for (int i = 0; i < C; ++i) {
        float v = -INFINITY;
        if (lane < count) v = bf2f(simS[i * 128 + lane]);
        if ((accMask >> lane) & 1ull) v = fmaxf(v, bf2f(simS[i * 128 + 64 + lane]));
#pragma unroll
        for (int off = 32; off > 0; off >>= 1) v = fmaxf(v, __shfl_xor(v, off, 64));
        const int total = count + nacc;
        const bool ok = (total == 0) || (v <= 0.8f);
        if (total < 64 && ok) {
          if (lane == 0) { selT[total] = sortedIdx[p + i]; newPos[nacc] = (ushort_t)i; }
          accMask |= (1ull << i);
          ++nacc;
          if (total + 1 == 64) break;
        }
      }
      if (lane == 0) { s_nacc = nacc; s_count = count + nacc; }
    }
    __syncthreads();

    {
      const int nacc = s_nacc;
      for (int a = wid; a < nacc; a += 4) {
        const int srcrow = 64 + (int)newPos[a];
        const int dstrow = count + a;
        const u16x8 val = *(const u16x8*)(allH + srcrow * 520 + lane * 8);
        *(u16x8*)(allH + dstrow * 520 + lane * 8) = val;
      }
    }
    p += C;
    __syncthreads();
  }

  __syncthreads();
  if (tid < 64) selidx_g[b * 64 + tid] = (tid < s_count) ? (int)selT[tid] : 0;
  if (tid == 0) selcnt_g[b] = s_count;
}

// q = hidden[:, T-2, :] @ q_w^T + q_b ; one wave per output element
__global__ __launch_bounds__(256)
void q_k(const float* __restrict__ hidden, const float* __restrict__ q_w,
         const float* __restrict__ q_b, float* __restrict__ qv)
{
  const int wid = threadIdx.x >> 6, lane = threadIdx.x & 63;
  const int o = blockIdx.x * 4 + wid;
  const int b = o >> 9, n = o & 511;
  const float* hr = hidden + ((size_t)b*1024 + 1022) * 512;
  const float* wr = q_w + (size_t)n * 512;
  const float4 h0 = *(const float4*)(hr + lane*4);
  const float4 h1 = *(const float4*)(hr + 256 + lane*4);
  const float4 w0 = *(const float4*)(wr + lane*4);
  const float4 w1 = *(const float4*)(wr + 256 + lane*4);
  float d = h0.x*w0.x + h0.y*w0.y + h0.z*w0.z + h0.w*w0.w
          + h1.x*w1.x + h1.y*w1.y + h1.z*w1.z + h1.w*w1.w;
  d = wsum64(d);
  if (lane == 0) qv[o] = d + q_b[n];
}

// masked softmax attention over selected memory; one block per batch
__global__ __launch_bounds__(256)
void attn_k(const float* __restrict__ hidden, const float* __restrict__ qv,
            const int* __restrict__ selidx_g, const int* __restrict__ selcnt_g,
            float* __restrict__ ctx)
{
  const int b = blockIdx.x, tid = threadIdx.x;
  const int wid = tid >> 6, lane = tid & 63;
  __shared__ float qs[512];
  __shared__ int sidx[64];
  __shared__ float sv[64];
  __shared__ float av[64];
  const int count = selcnt_g[b];
  for (int i = tid; i < 512; i += 256) qs[i] = qv[b*512 + i];
  if (tid < 64) sidx[tid] = selidx_g[b*64 + tid];
  __syncthreads();
  for (int m = wid; m < 64; m += 4) {
    float sval = -1e9f;
    if (m < count) {
      const float* hr = hidden + ((size_t)b*1024 + sidx[m]) * 512;
      const float4 a0 = *(const float4*)(hr + lane*4);
      const float4 a1 = *(const float4*)(hr + 256 + lane*4);
      const float4 q0 = *(const float4*)(&qs[lane*4]);
      const float4 q1 = *(const float4*)(&qs[256 + lane*4]);
      float d = a0.x*q0.x + a0.y*q0.y + a0.z*q0.z + a0.w*q0.w
              + a1.x*q1.x + a1.y*q1.y + a1.z*q1.z + a1.w*q1.w;
      d = wsum64(d);
      sval = d;
    }
    if (lane == 0) sv[m] = sval;
  }
  __syncthreads();
  if (tid < 64) {
    const float v = sv[tid];
    float mx = v;
#pragma unroll
    for (int off = 32; off > 0; off >>= 1) mx = fmaxf(mx, __shfl_xor(mx, off, 64));
    const float e = expf(v - mx);
    float ssum = e;
#pragma unroll
    for (int off = 32; off > 0; off >>= 1) ssum += __shfl_xor(ssum, off, 64);
    av[tid] = e / ssum;
  }
  __syncthreads();
  for (int n = tid; n < 512; n += 256) {
    float a = 0.f;
    for (int m = 0; m < count; ++m)
      a += av[m] * hidden[((size_t)b*1024 + sidx[m]) * 512 + n];
    ctx[b*512 + n] = a;
  }
}

// out = ctx @ out_w^T + out_b ; 16 vocab rows x all 32 batches per block
__global__ __launch_bounds__(256)
void out_k(const float* __restrict__ ctx, const float* __restrict__ out_w,
           const float* __restrict__ out_b, float* __restrict__ out)
{
  __shared__ float ctxT[512][33];
  const int tid = threadIdx.x;
  const int v0 = blockIdx.x * 16;
  for (int i = tid; i < 4096; i += 256) {
    const int bb = i & 31;
    const int k4 = (i >> 5) * 4;
    const float4 v = *(const float4*)(ctx + (size_t)bb * 512 + k4);
    ctxT[k4+0][bb] = v.x; ctxT[k4+1][bb] = v.y;
    ctxT[k4+2][bb] = v.z; ctxT[k4+3][bb] = v.w;
  }
  __syncthreads();
  const int bb = tid & 31;
  const int ty = tid >> 5;
#pragma unroll
  for (int vi = 0; vi < 2; ++vi) {
    const int v = v0 + vi * 8 + ty;
    const float* wr = out_w + (size_t)v * 512;
    float acc = 0.f;
#pragma unroll 4
    for (int k = 0; k < 512; k += 4) {
      const float4 w4 = *(const float4*)(wr + k);
      acc = fmaf(w4.x, ctxT[k+0][bb], acc);
      acc = fmaf(w4.y, ctxT[k+1][bb], acc);
      acc = fmaf(w4.z, ctxT[k+2][bb], acc);
      acc = fmaf(w4.w, ctxT[k+3][bb], acc);
    }
    out[(size_t)bb * 32000 + v] = acc + out_b[v];
  }
}

extern "C" void kernel_launch(void* const* d_in, const int* in_sizes, int n_in,
                              void* d_out, int out_size, void* d_ws, size_t ws_size,
                              hipStream_t stream)
{
  const int*   seq   = (const int*)d_in[0];
  const float* embed = (const float*)d_in[1];
  const float* w1    = (const float*)d_in[2];
  const float* b1    = (const float*)d_in[3];
  const float* w2    = (const float*)d_in[4];
  const float* b2    = (const float*)d_in[5];
  const float* ln_g  = (const float*)d_in[6];
  const float* ln_b  = (const float*)d_in[7];
  const float* wg_w  = (const float*)d_in[8];
  const float* wg_b  = (const float*)d_in[9];
  const float* q_w   = (const float*)d_in[10];
  const float* q_b   = (const float*)d_in[11];
  const float* out_w = (const float*)d_in[12];
  const float* out_b = (const float*)d_in[13];
  float* out = (float*)d_out;

  char* ws = (char*)d_ws;
  size_t off = 0;
  auto alloc = [&](size_t bytes) {
    void* p = ws + off;
    off += (bytes + 255) & ~(size_t)255;
    return p;
  };
  // Ahid/Alid (pre-split gathered hidden input) alias xbuf: dead after FF1.
  void* xA = alloc((size_t)32768 * 512 * 4);            // 67 MB
  ushort_t* Ahid = (ushort_t*)xA;
  ushort_t* Alid = Ahid + (size_t)32768 * 512;
  float* xbuf = (float*)xA;
  ushort_t* ff1h = (ushort_t*)alloc((size_t)32768 * 1024 * 2);  // 67 MB
  ushort_t* ff1l = (ushort_t*)alloc((size_t)32768 * 1024 * 2);  // 67 MB
  ushort_t* w1h = (ushort_t*)alloc((size_t)1024 * 512 * 2);
  ushort_t* w1l = (ushort_t*)alloc((size_t)1024 * 512 * 2);
  ushort_t* w2h = (ushort_t*)alloc((size_t)512 * 1024 * 2);
  ushort_t* w2l = (ushort_t*)alloc((size_t)512 * 1024 * 2);
  float* scores = (float*)alloc((size_t)32 * 1021 * 4);
  float* norms  = (float*)alloc((size_t)32 * 1021 * 4);
  int*   selidx = (int*)alloc((size_t)32 * 64 * 4);
  int*   selcnt = (int*)alloc((size_t)32 * 4);
  float* qbuf   = (float*)alloc((size_t)32 * 512 * 4);
  float* ctxb   = (float*)alloc((size_t)32 * 512 * 4);

  // pre-split passes
  gather_split<<<8192, 256, 0, stream>>>(seq, embed, Ahid, Alid);
  split_w<<<256, 256, 0, stream>>>(w1, w1h, w1l, 65536);
  split_w<<<256, 256, 0, stream>>>(w2, w2h, w2l, 65536);

  // FF1: relu(h @ w1^T + b1) -> ff1 hi/lo bf16   [32768,1024]
  gemm8<0><<<512, 512, 0, stream>>>(Ahid, Alid, w1h, w1l, b1,
                                    nullptr, nullptr, ff1h, ff1l, nullptr,
                                    1024, 512);
  // FF2: ff1 @ w2^T + b2 + embed[seq] -> xbuf f32 [32768,512]
  gemm8<1><<<256, 512, 0, stream>>>(ff1h, ff1l, w2h, w2l, b2,
                                    seq, embed, nullptr, nullptr, xbuf,
                                    512, 1024);
  // LayerNorm in place + fused scores/norms
  lnscore_k<<<8192, 256, 0, stream>>>(xbuf, ln_g, ln_b, wg_w, wg_b, scores, norms);
  // greedy dedup selection
  select_k<<<32, 256, 0, stream>>>(xbuf, scores, norms, selidx, selcnt);
  // q projection for query row (t = 1022)
  q_k<<<4096, 256, 0, stream>>>(xbuf, q_w, q_b, qbuf);
  // attention over selected memory -> ctx
  attn_k<<<32, 256, 0, stream>>>(xbuf, qbuf, selidx, selcnt, ctxb);
  // final vocab projection
  out_k<<<2000, 256, 0, stream>>>(ctxb, out_w, out_b, out);
}

// Round 7
// 379.518 us; speedup vs baseline: 1.4089x; 1.2702x over previous
//
#include <hip/hip_runtime.h>
#include <math.h>

typedef unsigned short ushort_t;
typedef short bf16x8 __attribute__((ext_vector_type(8)));
typedef unsigned short u16x8 __attribute__((ext_vector_type(8)));
typedef float f32x4 __attribute__((ext_vector_type(4)));

__device__ __forceinline__ float wsum64(float v) {
#pragma unroll
  for (int off = 32; off > 0; off >>= 1) v += __shfl_xor(v, off, 64);
  return v;
}

__device__ __forceinline__ ushort_t f2bf(float x) {   // RNE f32->bf16
  unsigned u = __float_as_uint(x);
  return (ushort_t)((u + 0x7fffu + ((u >> 16) & 1u)) >> 16);
}
__device__ __forceinline__ float bf2f(ushort_t h) {
  return __uint_as_float(((unsigned)h) << 16);
}

__device__ __forceinline__ void split8(const float4 a, const float4 b,
                                       u16x8& h, u16x8& l) {
  h[0]=f2bf(a.x); l[0]=f2bf(a.x-bf2f(h[0]));
  h[1]=f2bf(a.y); l[1]=f2bf(a.y-bf2f(h[1]));
  h[2]=f2bf(a.z); l[2]=f2bf(a.z-bf2f(h[2]));
  h[3]=f2bf(a.w); l[3]=f2bf(a.w-bf2f(h[3]));
  h[4]=f2bf(b.x); l[4]=f2bf(b.x-bf2f(h[4]));
  h[5]=f2bf(b.y); l[5]=f2bf(b.y-bf2f(h[5]));
  h[6]=f2bf(b.z); l[6]=f2bf(b.z-bf2f(h[6]));
  h[7]=f2bf(b.w); l[7]=f2bf(b.w-bf2f(h[7]));
}

// async global(per-lane) -> LDS(wave-uniform base + lane*16B), 16B per lane
__device__ __forceinline__ void gl16(const void* g, const void* l) {
  __builtin_amdgcn_global_load_lds(
      (const __attribute__((address_space(1))) unsigned int*)g,
      (__attribute__((address_space(3))) unsigned int*)l, 16, 0, 0);
}

#define SBAR __builtin_amdgcn_sched_barrier(0)
#define BARRIER __builtin_amdgcn_s_barrier()
#define LGKM0 asm volatile("s_waitcnt lgkmcnt(0)" ::: "memory")
#define VMC6 asm volatile("s_waitcnt vmcnt(6)" ::: "memory")
#define VMC0 asm volatile("s_waitcnt vmcnt(0)" ::: "memory")

// ---------------------------------------------------------------------------
// gather-split: Ah/Al[row][512] bf16 hi/lo of embed[seq[row]]
// ---------------------------------------------------------------------------
__global__ __launch_bounds__(256)
void gather_split(const int* __restrict__ seq, const float* __restrict__ embed,
                  ushort_t* __restrict__ Ah, ushort_t* __restrict__ Al)
{
  const int wid = threadIdx.x >> 6, lane = threadIdx.x & 63;
  const int row = blockIdx.x * 4 + wid;
  const float* src = embed + (size_t)seq[row] * 512 + lane * 8;
  const float4 a = *(const float4*)src;
  const float4 b = *(const float4*)(src + 4);
  u16x8 h, l;
  split8(a, b, h, l);
  *(u16x8*)(Ah + (size_t)row * 512 + lane * 8) = h;
  *(u16x8*)(Al + (size_t)row * 512 + lane * 8) = l;
}

// elementwise weight split (n8 = total_elems/8)
__global__ __launch_bounds__(256)
void split_w(const float* __restrict__ W, ushort_t* __restrict__ Wh,
             ushort_t* __restrict__ Wl, int n8)
{
  const int i = blockIdx.x * 256 + threadIdx.x;
  if (i >= n8) return;
  const float4 a = *(const float4*)(W + (size_t)i * 8);
  const float4 b = *(const float4*)(W + (size_t)i * 8 + 4);
  u16x8 h, l;
  split8(a, b, h, l);
  *(u16x8*)(Wh + (size_t)i * 8) = h;
  *(u16x8*)(Wl + (size_t)i * 8) = l;
}

// ---------------------------------------------------------------------------
// Split-bf16 MFMA GEMM, 8-phase schedule (T3+T4+T5, m201 template).
// (unchanged from round 6 — see comments there)
// ---------------------------------------------------------------------------
template<int EPI>
__global__ __launch_bounds__(512, 1)
void gemm8(const ushort_t* __restrict__ Ah, const ushort_t* __restrict__ Al,
           const ushort_t* __restrict__ Bh, const ushort_t* __restrict__ Bl,
           const float* __restrict__ bias,
           const int* __restrict__ seq, const float* __restrict__ embed,
           ushort_t* __restrict__ Oh, ushort_t* __restrict__ Ol,
           float* __restrict__ Of, int N, int K)
{
  __shared__ __align__(16) ushort_t lds[65536];   // 128 KB
  const int tid = threadIdx.x;
  const int numN = N >> 8;
  int bid = blockIdx.x;
  {  // XCD-aware swizzle (grids are multiples of 8)
    const int chunk = gridDim.x >> 3;
    bid = (bid & 7) * chunk + (bid >> 3);
  }
  const int m0 = (bid / numN) << 8;
  const int n0 = (bid % numN) << 8;
  const int wid = tid >> 6, lane = tid & 63;
  const int wm = wid >> 2, wn = wid & 3;
  const int l16 = lane & 15, lkb = lane >> 4;

  const int tpt = K >> 6;       // real-K tiles per third
  const int NT  = 3 * tpt;      // virtual tiles
  const int NI  = NT >> 1;      // iterations (2 tiles each)

  int srcA[2][2], srcB[2][2];   // [h][j] element offsets (row*K + col)
  {
    const int c0 = wid * 64 + lane;
#pragma unroll
    for (int j = 0; j < 2; ++j) {
      const int c = c0 + j * 512;
      const int lr = c >> 3, ch = c & 7;
#pragma unroll
      for (int h = 0; h < 2; ++h) {
        const int lrow = h * 128 + lr;
        const int col = ((ch ^ (lrow & 7)) << 3);
        const int rA = (lrow & 63) | ((lrow & 64) << 1) | ((lrow & 128) >> 1);
        const int rB = ((lrow >> 5) & 3) * 64 + (lrow >> 7) * 32 + (lrow & 31);
        srcA[h][j] = rA * K + col;
        srcB[h][j] = rB * K + col;
      }
    }
  }
  const size_t aRow0 = (size_t)m0 * K;
  const size_t bRow0 = (size_t)n0 * K;

  auto stageH = [&](int ts, int matH) {   // matH: 0=(A,h0) 1=(B,h0) 2=(A,h1) 3=(B,h1)
    const int mat = matH & 1, h = matH >> 1;
    const int th = (ts >= tpt) + (ts >= 2 * tpt);
    const int kb = (ts - th * tpt) << 6;
    ushort_t* dst = lds + ((ts & 1) << 15) + mat * 16384 + h * 8192 + wid * 512;
    if (mat == 0) {
      const ushort_t* bp = ((th == 1) ? Al : Ah) + aRow0 + kb;
      gl16(bp + srcA[h][0], dst);
      gl16(bp + srcA[h][1], dst + 4096);
    } else {
      const ushort_t* bp = ((th == 2) ? Bl : Bh) + bRow0 + kb;
      gl16(bp + srcB[h][0], dst);
      gl16(bp + srcB[h][1], dst + 4096);
    }
  };

  const int swz = l16 & 7;
  int cSwz[2];
  cSwz[0] = ((lkb ^ swz) << 3);
  cSwz[1] = (((4 + lkb) ^ swz) << 3);
  const int aLane = (wm * 64 + l16) * 64;
  const int bLane = 16384 + (wn * 32 + l16) * 64;

  bf16x8 fa[4][2], fb0[2][2], fb1[2][2];
  f32x4 acc[8][4];
#pragma unroll
  for (int m = 0; m < 8; ++m)
#pragma unroll
    for (int n = 0; n < 4; ++n) acc[m][n] = (f32x4){0.f, 0.f, 0.f, 0.f};

  auto loadA = [&](int doff, int qm) {
#pragma unroll
    for (int m = 0; m < 4; ++m)
#pragma unroll
      for (int ks = 0; ks < 2; ++ks)
        fa[m][ks] = *(const bf16x8*)(lds + doff + qm * 8192 + aLane + m * 1024 + cSwz[ks]);
  };
  auto loadB = [&](int doff, int qn, bf16x8 (*fb)[2]) {
#pragma unroll
    for (int nf = 0; nf < 2; ++nf)
#pragma unroll
      for (int ks = 0; ks < 2; ++ks)
        fb[nf][ks] = *(const bf16x8*)(lds + doff + qn * 8192 + bLane + nf * 1024 + cSwz[ks]);
  };
  auto mfmaQ = [&](int qm, int qn, bf16x8 (*fb)[2]) {
    __builtin_amdgcn_s_setprio(1);
#pragma unroll
    for (int m = 0; m < 4; ++m)
#pragma unroll
      for (int nf = 0; nf < 2; ++nf) {
        f32x4 a = acc[qm * 4 + m][qn * 2 + nf];
        a = __builtin_amdgcn_mfma_f32_16x16x32_bf16(fa[m][0], fb[nf][0], a, 0, 0, 0);
        a = __builtin_amdgcn_mfma_f32_16x16x32_bf16(fa[m][1], fb[nf][1], a, 0, 0, 0);
        acc[qm * 4 + m][qn * 2 + nf] = a;
      }
    __builtin_amdgcn_s_setprio(0);
  };

  stageH(0, 0); stageH(0, 1); stageH(0, 2); stageH(0, 3);
  stageH(1, 0); stageH(1, 1);
  asm volatile("s_waitcnt vmcnt(4)" ::: "memory");
  BARRIER; SBAR;

  for (int i = 0; i < NI; ++i) {
    const int t1 = 2 * i + 1, t2 = 2 * i + 2, t3 = 2 * i + 3;
    const bool more = (i + 1 < NI);
    loadA(0, 0); loadB(0, 0, fb0); stageH(t1, 2); SBAR; VMC6;
    BARRIER; LGKM0; SBAR; mfmaQ(0, 0, fb0); BARRIER;
    loadB(0, 1, fb1); stageH(t1, 3); SBAR;
    BARRIER; LGKM0; SBAR; mfmaQ(0, 1, fb1); BARRIER;
    loadA(0, 1); if (more) stageH(t2, 0); SBAR;
    BARRIER; LGKM0; SBAR; mfmaQ(1, 0, fb0); BARRIER;
    if (more) stageH(t2, 1); SBAR;
    BARRIER; LGKM0; SBAR; mfmaQ(1, 1, fb1); BARRIER;
    loadA(32768, 0); loadB(32768, 0, fb0);
    if (more) { stageH(t2, 2); SBAR; VMC6; }
    else      { SBAR; VMC0; }
    BARRIER; LGKM0; SBAR; mfmaQ(0, 0, fb0); BARRIER;
    loadB(32768, 1, fb1); if (more) stageH(t2, 3); SBAR;
    BARRIER; LGKM0; SBAR; mfmaQ(0, 1, fb1); BARRIER;
    loadA(32768, 1); if (more) stageH(t3, 0); SBAR;
    BARRIER; LGKM0; SBAR; mfmaQ(1, 0, fb0); BARRIER;
    if (more) stageH(t3, 1); SBAR;
    BARRIER; LGKM0; SBAR; mfmaQ(1, 1, fb1); BARRIER;
  }

  if (EPI == 0) {
    unsigned* pw = (unsigned*)lds + wid * 4096;
    float bv[4];
#pragma unroll
    for (int n = 0; n < 4; ++n) bv[n] = bias[n0 + wn * 64 + n * 16 + l16];
#pragma unroll
    for (int half = 0; half < 2; ++half) {
#pragma unroll
      for (int m = 0; m < 4; ++m) {
        const int mg = half * 4 + m;
#pragma unroll
        for (int n = 0; n < 4; ++n)
#pragma unroll
          for (int i = 0; i < 4; ++i) {
            float v = fmaxf(acc[mg][n][i] + bv[n], 0.f);
            const ushort_t h = f2bf(v);
            const ushort_t l = f2bf(v - bf2f(h));
            const int row = m * 16 + lkb * 4 + i;
            pw[row * 64 + n * 16 + l16] = ((unsigned)h << 16) | l;
          }
      }
#pragma unroll
      for (int p = 0; p < 16; ++p) {
        const int idx = p * 256 + lane * 4;
        const int row = idx >> 6, col = idx & 63;
        const uint4 w = *(const uint4*)(pw + idx);
        ushort4 hs, ls;
        hs.x = (ushort_t)(w.x >> 16); ls.x = (ushort_t)(w.x & 0xffffu);
        hs.y = (ushort_t)(w.y >> 16); ls.y = (ushort_t)(w.y & 0xffffu);
        hs.z = (ushort_t)(w.z >> 16); ls.z = (ushort_t)(w.z & 0xffffu);
        hs.w = (ushort_t)(w.w >> 16); ls.w = (ushort_t)(w.w & 0xffffu);
        const size_t go = (size_t)(m0 + wm * 128 + half * 64 + row) * N
                          + (n0 + wn * 64 + col);
        *(ushort4*)(Oh + go) = hs;
        *(ushort4*)(Ol + go) = ls;
      }
    }
  } else {
#pragma unroll
    for (int n = 0; n < 4; ++n) {
      const int col = n0 + wn * 64 + n * 16 + l16;
      const float bvv = bias[col];
#pragma unroll
      for (int m = 0; m < 8; ++m) {
        const int rbase = m0 + wm * 128 + m * 16 + lkb * 4;
#pragma unroll
        for (int i = 0; i < 4; ++i) {
          const int row = rbase + i;
          float v = acc[m][n][i] + bvv;
          v += embed[(size_t)seq[row] * 512 + col];
          Of[(size_t)row * N + col] = v;
        }
      }
    }
  }
}

// in-place LayerNorm + fused gate score + L2 norm; one wave per 512-elem row
__global__ __launch_bounds__(256)
void lnscore_k(float* __restrict__ x, const float* __restrict__ g,
               const float* __restrict__ bt, const float* __restrict__ wg_w,
               const float* __restrict__ wg_b, float* __restrict__ scores,
               float* __restrict__ norms)
{
  const int wid = threadIdx.x >> 6, lane = threadIdx.x & 63;
  const int row = blockIdx.x * 4 + wid;
  float* xr = x + (size_t)row * 512;
  const float4 v0 = *(const float4*)(xr + lane*4);
  const float4 v1 = *(const float4*)(xr + 256 + lane*4);
  float s = v0.x+v0.y+v0.z+v0.w + v1.x+v1.y+v1.z+v1.w;
  s = wsum64(s);
  const float mu = s * (1.f/512.f);
  float ss = (v0.x-mu)*(v0.x-mu) + (v0.y-mu)*(v0.y-mu)
           + (v0.z-mu)*(v0.z-mu) + (v0.w-mu)*(v0.w-mu)
           + (v1.x-mu)*(v1.x-mu) + (v1.y-mu)*(v1.y-mu)
           + (v1.z-mu)*(v1.z-mu) + (v1.w-mu)*(v1.w-mu);
  ss = wsum64(ss);
  const float inv = 1.f / sqrtf(ss * (1.f/512.f) + 1e-5f);
  const float4 g0 = *(const float4*)(g + lane*4);
  const float4 g1 = *(const float4*)(g + 256 + lane*4);
  const float4 c0 = *(const float4*)(bt + lane*4);
  const float4 c1 = *(const float4*)(bt + 256 + lane*4);
  float4 o0, o1;
  o0.x = (v0.x-mu)*inv*g0.x + c0.x;  o0.y = (v0.y-mu)*inv*g0.y + c0.y;
  o0.z = (v0.z-mu)*inv*g0.z + c0.z;  o0.w = (v0.w-mu)*inv*g0.w + c0.w;
  o1.x = (v1.x-mu)*inv*g1.x + c1.x;  o1.y = (v1.y-mu)*inv*g1.y + c1.y;
  o1.z = (v1.z-mu)*inv*g1.z + c1.z;  o1.w = (v1.w-mu)*inv*g1.w + c1.w;
  *(float4*)(xr + lane*4) = o0;
  *(float4*)(xr + 256 + lane*4) = o1;

  const float4 q0 = *(const float4*)(wg_w + lane*4);
  const float4 q1 = *(const float4*)(wg_w + 256 + lane*4);
  float d = o0.x*q0.x + o0.y*q0.y + o0.z*q0.z + o0.w*q0.w
          + o1.x*q1.x + o1.y*q1.y + o1.z*q1.z + o1.w*q1.w;
  float n2 = o0.x*o0.x + o0.y*o0.y + o0.z*o0.z + o0.w*o0.w
           + o1.x*o1.x + o1.y*o1.y + o1.z*o1.z + o1.w*o1.w;
  d = wsum64(d); n2 = wsum64(n2);
  const int b = row >> 10, t = row & 1023;
  if (lane == 0 && t < 1021) {
    scores[b * 1021 + t] = d + wg_b[0];
    norms[b * 1021 + t] = sqrtf(n2);
  }
}

// ---------------------------------------------------------------------------
// Greedy score-ranked selection with cosine dedup; one block per batch row.
// ---------------------------------------------------------------------------
__global__ __launch_bounds__(256, 1)
void select_k(const float* __restrict__ hidden, const float* __restrict__ scores,
              const float* __restrict__ norms, int* __restrict__ selidx_g,
              int* __restrict__ selcnt_g)
{
  __shared__ __align__(16) ushort_t allH[128 * 520];     // 133120 B (keys alias)
  __shared__ ushort_t simS[64 * 128];
  __shared__ ushort_t sortedIdx[1024];
  __shared__ ushort_t selT[64];
  __shared__ ushort_t newPos[64];
  __shared__ int s_count, s_nacc;

  const int b = blockIdx.x, tid = threadIdx.x;
  const int wid = tid >> 6, lane = tid & 63;
  const int l16 = lane & 15, lkb = lane >> 4;

  unsigned long long* keys = (unsigned long long*)allH;
  for (int i = tid; i < 1024; i += 256) {
    const float s = (i < 1021) ? scores[b * 1021 + i] : -INFINITY;
    const unsigned u = __float_as_uint(s);
    const unsigned ms = (u & 0x80000000u) ? ~u : (u | 0x80000000u);
    keys[i] = ((unsigned long long)(~ms) << 32) | (unsigned)i;
  }
  __syncthreads();
  for (int k = 2; k <= 1024; k <<= 1) {
    for (int j = k >> 1; j > 0; j >>= 1) {
      for (int i = tid; i < 1024; i += 256) {
        const int ixj = i ^ j;
        if (ixj > i) {
          const unsigned long long a = keys[i], c = keys[ixj];
          const bool up = ((i & k) == 0);
          if ((a > c) == up) { keys[i] = c; keys[ixj] = a; }
        }
      }
      __syncthreads();
    }
  }
  for (int i = tid; i < 1024; i += 256)
    sortedIdx[i] = (ushort_t)(keys[i] & 0xffffu);
  if (tid == 0) s_count = 0;
  __syncthreads();

  int p = 0;
  while (true) {
    const int count = s_count;
    if (count >= 64 || p >= 1021) break;
    const int C = min(64, 1021 - p);

    {
      const int r = tid >> 2;
      const int seg = (tid & 3) * 128;
      if (r < C) {
        const int t = sortedIdx[p + r];
        const float rn = 1.f / fmaxf(norms[b * 1021 + t], 1e-12f);
        const float* src = hidden + ((size_t)b * 1024 + t) * 512 + seg;
        ushort_t* dst = allH + (64 + r) * 520 + seg;
#pragma unroll
        for (int u0 = 0; u0 < 128; u0 += 8) {
          const float4 x = *(const float4*)(src + u0);
          const float4 y = *(const float4*)(src + u0 + 4);
          u16x8 o;
          o[0] = f2bf(x.x * rn); o[1] = f2bf(x.y * rn);
          o[2] = f2bf(x.z * rn); o[3] = f2bf(x.w * rn);
          o[4] = f2bf(y.x * rn); o[5] = f2bf(y.y * rn);
          o[6] = f2bf(y.z * rn); o[7] = f2bf(y.w * rn);
          *(u16x8*)(dst + u0) = o;
        }
      }
    }
    __syncthreads();

    {
      f32x4 acc[8];
#pragma unroll
      for (int t = 0; t < 8; ++t) acc[t] = (f32x4){0.f, 0.f, 0.f, 0.f};
      const ushort_t* Abase = allH + (64 + (wid << 4) + l16) * 520;
#pragma unroll
      for (int ks = 0; ks < 16; ++ks) {
        const bf16x8 a = *(const bf16x8*)(Abase + ks * 32 + lkb * 8);
#pragma unroll
        for (int t = 0; t < 8; ++t) {
          const bf16x8 bb = *(const bf16x8*)(allH + ((t << 4) + l16) * 520 + ks * 32 + lkb * 8);
          acc[t] = __builtin_amdgcn_mfma_f32_16x16x32_bf16(a, bb, acc[t], 0, 0, 0);
        }
      }
#pragma unroll
      for (int t = 0; t < 8; ++t)
#pragma unroll
        for (int ii = 0; ii < 4; ++ii) {
          const int ri = (wid << 4) + lkb * 4 + ii;
          simS[ri * 128 + (t << 4) + l16] = f2bf(acc[t][ii]);
        }
    }
    __syncthreads();

    if (wid == 0) {
      unsigned long long accMask = 0ull;
      int nacc = 0;
      for (int i = 0; i < C; ++i) {
        float v = -INFINITY;
        if (lane < count) v = bf2f(simS[i * 128 + lane]);
        if ((accMask >> lane) & 1ull) v = fmaxf(v, bf2f(simS[i * 128 + 64 + lane]));
#pragma unroll
        for (int off = 32; off > 0; off >>= 1) v = fmaxf(v, __shfl_xor(v, off, 64));
        const int total = count + nacc;
        const bool ok = (total == 0) || (v <= 0.8f);
        if (total < 64 && ok) {
          if (lane == 0) { selT[total] = sortedIdx[p + i]; newPos[nacc] = (ushort_t)i; }
          accMask |= (1ull << i);
          ++nacc;
          if (total + 1 == 64) break;
        }
      }
      if (lane == 0) { s_nacc = nacc; s_count = count + nacc; }
    }
    __syncthreads();

    {
      const int nacc = s_nacc;
      for (int a = wid; a < nacc; a += 4) {
        const int srcrow = 64 + (int)newPos[a];
        const int dstrow = count + a;
        const u16x8 val = *(const u16x8*)(allH + srcrow * 520 + lane * 8);
        *(u16x8*)(allH + dstrow * 520 + lane * 8) = val;
      }
    }
    p += C;
    __syncthreads();
  }

  __syncthreads();
  if (tid < 64) selidx_g[b * 64 + tid] = (tid < s_count) ? (int)selT[tid] : 0;
  if (tid == 0) selcnt_g[b] = s_count;
}

// q = hidden[:, T-2, :] @ q_w^T + q_b ; one wave per output element
__global__ __launch_bounds__(256)
void q_k(const float* __restrict__ hidden, const float* __restrict__ q_w,
         const float* __restrict__ q_b, float* __restrict__ qv)
{
  const int wid = threadIdx.x >> 6, lane = threadIdx.x & 63;
  const int o = blockIdx.x * 4 + wid;
  const int b = o >> 9, n = o & 511;
  const float* hr = hidden + ((size_t)b*1024 + 1022) * 512;
  const float* wr = q_w + (size_t)n * 512;
  const float4 h0 = *(const float4*)(hr + lane*4);
  const float4 h1 = *(const float4*)(hr + 256 + lane*4);
  const float4 w0 = *(const float4*)(wr + lane*4);
  const float4 w1 = *(const float4*)(wr + 256 + lane*4);
  float d = h0.x*w0.x + h0.y*w0.y + h0.z*w0.z + h0.w*w0.w
          + h1.x*w1.x + h1.y*w1.y + h1.z*w1.z + h1.w*w1.w;
  d = wsum64(d);
  if (lane == 0) qv[o] = d + q_b[n];
}

// masked softmax attention over selected memory; one block per batch
__global__ __launch_bounds__(256)
void attn_k(const float* __restrict__ hidden, const float* __restrict__ qv,
            const int* __restrict__ selidx_g, const int* __restrict__ selcnt_g,
            float* __restrict__ ctx)
{
  const int b = blockIdx.x, tid = threadIdx.x;
  const int wid = tid >> 6, lane = tid & 63;
  __shared__ float qs[512];
  __shared__ int sidx[64];
  __shared__ float sv[64];
  __shared__ float av[64];
  const int count = selcnt_g[b];
  for (int i = tid; i < 512; i += 256) qs[i] = qv[b*512 + i];
  if (tid < 64) sidx[tid] = selidx_g[b*64 + tid];
  __syncthreads();
  for (int m = wid; m < 64; m += 4) {
    float sval = -1e9f;
    if (m < count) {
      const float* hr = hidden + ((size_t)b*1024 + sidx[m]) * 512;
      const float4 a0 = *(const float4*)(hr + lane*4);
      const float4 a1 = *(const float4*)(hr + 256 + lane*4);
      const float4 q0 = *(const float4*)(&qs[lane*4]);
      const float4 q1 = *(const float4*)(&qs[256 + lane*4]);
      float d = a0.x*q0.x + a0.y*q0.y + a0.z*q0.z + a0.w*q0.w
              + a1.x*q1.x + a1.y*q1.y + a1.z*q1.z + a1.w*q1.w;
      d = wsum64(d);
      sval = d;
    }
    if (lane == 0) sv[m] = sval;
  }
  __syncthreads();
  if (tid < 64) {
    const float v = sv[tid];
    float mx = v;
#pragma unroll
    for (int off = 32; off > 0; off >>= 1) mx = fmaxf(mx, __shfl_xor(mx, off, 64));
    const float e = expf(v - mx);
    float ssum = e;
#pragma unroll
    for (int off = 32; off > 0; off >>= 1) ssum += __shfl_xor(ssum, off, 64);
    av[tid] = e / ssum;
  }
  __syncthreads();
  for (int n = tid; n < 512; n += 256) {
    float a = 0.f;
    for (int m = 0; m < count; ++m)
      a += av[m] * hidden[((size_t)b*1024 + sidx[m]) * 512 + n];
    ctx[b*512 + n] = a;
  }
}

// ---------------------------------------------------------------------------
// out = ctx @ out_w^T + out_b via streaming split-bf16 MFMA.
// M=32 (2 m-frags), per wave one 16-vocab tile over K=512. out_w streamed
// f32 coalesced, converted hi/lo in-register; ctx hi/lo staged in LDS
// (pitch 520 u16 -> 2-way banked = free). 3-term split: ch*wh+cl*wh+ch*wl.
// grid 500 x 256.
// ---------------------------------------------------------------------------
__global__ __launch_bounds__(256, 2)
void out_k(const float* __restrict__ ctx, const float* __restrict__ out_w,
           const float* __restrict__ out_b, float* __restrict__ out)
{
  __shared__ __align__(16) ushort_t ctxH[32 * 520];
  __shared__ __align__(16) ushort_t ctxL[32 * 520];
  const int tid = threadIdx.x;
  const int wid = tid >> 6, lane = tid & 63;
  const int l16 = lane & 15, lkb = lane >> 4;

  // stage ctx hi/lo (32 rows x 512), thread: row tid>>3, cols (tid&7)*64..+64
  {
    const int row = tid >> 3;
    const int c0 = (tid & 7) * 64;
    const float* src = ctx + row * 512 + c0;
    ushort_t* dh = ctxH + row * 520 + c0;
    ushort_t* dl = ctxL + row * 520 + c0;
#pragma unroll
    for (int u0 = 0; u0 < 64; u0 += 8) {
      const float4 a = *(const float4*)(src + u0);
      const float4 b = *(const float4*)(src + u0 + 4);
      u16x8 h, l;
      split8(a, b, h, l);
      *(u16x8*)(dh + u0) = h;
      *(u16x8*)(dl + u0) = l;
    }
  }
  __syncthreads();

  const int v = blockIdx.x * 64 + wid * 16 + l16;
  const float* wr = out_w + (size_t)v * 512 + lkb * 8;
  f32x4 acc0 = (f32x4){0.f, 0.f, 0.f, 0.f};
  f32x4 acc1 = (f32x4){0.f, 0.f, 0.f, 0.f};
#pragma unroll
  for (int ks = 0; ks < 16; ++ks) {
    const float4 wa = *(const float4*)(wr + ks * 32);
    const float4 wb = *(const float4*)(wr + ks * 32 + 4);
    u16x8 wh, wl;
    split8(wa, wb, wh, wl);
    const bf16x8 whb = (bf16x8)wh, wlb = (bf16x8)wl;
    const int co = ks * 32 + lkb * 8;
    const bf16x8 ch0 = *(const bf16x8*)(ctxH + l16 * 520 + co);
    const bf16x8 cl0 = *(const bf16x8*)(ctxL + l16 * 520 + co);
    const bf16x8 ch1 = *(const bf16x8*)(ctxH + (16 + l16) * 520 + co);
    const bf16x8 cl1 = *(const bf16x8*)(ctxL + (16 + l16) * 520 + co);
    acc0 = __builtin_amdgcn_mfma_f32_16x16x32_bf16(ch0, whb, acc0, 0, 0, 0);
    acc0 = __builtin_amdgcn_mfma_f32_16x16x32_bf16(cl0, whb, acc0, 0, 0, 0);
    acc0 = __builtin_amdgcn_mfma_f32_16x16x32_bf16(ch0, wlb, acc0, 0, 0, 0);
    acc1 = __builtin_amdgcn_mfma_f32_16x16x32_bf16(ch1, whb, acc1, 0, 0, 0);
    acc1 = __builtin_amdgcn_mfma_f32_16x16x32_bf16(cl1, whb, acc1, 0, 0, 0);
    acc1 = __builtin_amdgcn_mfma_f32_16x16x32_bf16(ch1, wlb, acc1, 0, 0, 0);
  }
  // D layout: col (vocab) = l16 (already in v), row (batch) = lkb*4+i (+16)
  const float bv = out_b[v];
#pragma unroll
  for (int i = 0; i < 4; ++i) {
    out[(size_t)(lkb * 4 + i) * 32000 + v] = acc0[i] + bv;
    out[(size_t)(16 + lkb * 4 + i) * 32000 + v] = acc1[i] + bv;
  }
}

extern "C" void kernel_launch(void* const* d_in, const int* in_sizes, int n_in,
                              void* d_out, int out_size, void* d_ws, size_t ws_size,
                              hipStream_t stream)
{
  const int*   seq   = (const int*)d_in[0];
  const float* embed = (const float*)d_in[1];
  const float* w1    = (const float*)d_in[2];
  const float* b1    = (const float*)d_in[3];
  const float* w2    = (const float*)d_in[4];
  const float* b2    = (const float*)d_in[5];
  const float* ln_g  = (const float*)d_in[6];
  const float* ln_b  = (const float*)d_in[7];
  const float* wg_w  = (const float*)d_in[8];
  const float* wg_b  = (const float*)d_in[9];
  const float* q_w   = (const float*)d_in[10];
  const float* q_b   = (const float*)d_in[11];
  const float* out_w = (const float*)d_in[12];
  const float* out_b = (const float*)d_in[13];
  float* out = (float*)d_out;

  char* ws = (char*)d_ws;
  size_t off = 0;
  auto alloc = [&](size_t bytes) {
    void* p = ws + off;
    off += (bytes + 255) & ~(size_t)255;
    return p;
  };
  void* xA = alloc((size_t)32768 * 512 * 4);            // 67 MB
  ushort_t* Ahid = (ushort_t*)xA;
  ushort_t* Alid = Ahid + (size_t)32768 * 512;
  float* xbuf = (float*)xA;
  ushort_t* ff1h = (ushort_t*)alloc((size_t)32768 * 1024 * 2);  // 67 MB
  ushort_t* ff1l = (ushort_t*)alloc((size_t)32768 * 1024 * 2);  // 67 MB
  ushort_t* w1h = (ushort_t*)alloc((size_t)1024 * 512 * 2);
  ushort_t* w1l = (ushort_t*)alloc((size_t)1024 * 512 * 2);
  ushort_t* w2h = (ushort_t*)alloc((size_t)512 * 1024 * 2);
  ushort_t* w2l = (ushort_t*)alloc((size_t)512 * 1024 * 2);
  float* scores = (float*)alloc((size_t)32 * 1021 * 4);
  float* norms  = (float*)alloc((size_t)32 * 1021 * 4);
  int*   selidx = (int*)alloc((size_t)32 * 64 * 4);
  int*   selcnt = (int*)alloc((size_t)32 * 4);
  float* qbuf   = (float*)alloc((size_t)32 * 512 * 4);
  float* ctxb   = (float*)alloc((size_t)32 * 512 * 4);

  gather_split<<<8192, 256, 0, stream>>>(seq, embed, Ahid, Alid);
  split_w<<<256, 256, 0, stream>>>(w1, w1h, w1l, 65536);
  split_w<<<256, 256, 0, stream>>>(w2, w2h, w2l, 65536);

  gemm8<0><<<512, 512, 0, stream>>>(Ahid, Alid, w1h, w1l, b1,
                                    nullptr, nullptr, ff1h, ff1l, nullptr,
                                    1024, 512);
  gemm8<1><<<256, 512, 0, stream>>>(ff1h, ff1l, w2h, w2l, b2,
                                    seq, embed, nullptr, nullptr, xbuf,
                                    512, 1024);
  lnscore_k<<<8192, 256, 0, stream>>>(xbuf, ln_g, ln_b, wg_w, wg_b, scores, norms);
  select_k<<<32, 256, 0, stream>>>(xbuf, scores, norms, selidx, selcnt);
  q_k<<<4096, 256, 0, stream>>>(xbuf, q_w, q_b, qbuf);
  attn_k<<<32, 256, 0, stream>>>(xbuf, qbuf, selidx, selcnt, ctxb);
  out_k<<<500, 256, 0, stream>>>(ctxb, out_w, out_b, out);
}